// Round 2
// baseline (673.448 us; speedup 1.0000x reference)
//
#include <hip/hip_runtime.h>
#include <stdint.h>

// ---- problem dims ----
#define KD 1024   // input dim
#define KH 4096   // hidden dim
#define KO 1024   // expert output dim
#define KE 8      // experts
#define KT 4096   // tokens (B*S = 2*2048)

typedef unsigned short u16;
typedef __bf16 bf16x8 __attribute__((ext_vector_type(8)));
typedef unsigned short ushort8 __attribute__((ext_vector_type(8)));
typedef float floatx4 __attribute__((ext_vector_type(4)));

__device__ __forceinline__ u16 f2bf(float f) {
  unsigned u = __float_as_uint(f);
  u += 0x7fffu + ((u >> 16) & 1u);   // round-to-nearest-even
  return (u16)(u >> 16);
}

// direct global->LDS DMA, 16B per lane (HW dest = wave-uniform base + lane*16B)
__device__ __forceinline__ void glds16(const u16* g, u16* l) {
  __builtin_amdgcn_global_load_lds(
      (const __attribute__((address_space(1))) unsigned int*)(g),
      (__attribute__((address_space(3))) unsigned int*)(l), 16, 0, 0);
}

#define BAR __builtin_amdgcn_s_barrier()
#define SB0 __builtin_amdgcn_sched_barrier(0)

// ---------------- x -> bf16 ----------------
__global__ void cvt_x_k(const float* __restrict__ x, u16* __restrict__ xbf) {
  int i = blockIdx.x * blockDim.x + threadIdx.x;   // one float4 per thread
  float4 v = ((const float4*)x)[i];
  union { u16 u[4]; uint2 v2; } o;
  o.u[0] = f2bf(v.x); o.u[1] = f2bf(v.y); o.u[2] = f2bf(v.z); o.u[3] = f2bf(v.w);
  ((uint2*)xbf)[i] = o.v2;
}

// ------- transpose + convert: in[E][R][C] f32 -> out[E][C][R] bf16, 64x64 tiles -------
__global__ __launch_bounds__(256) void transpose_k(const float* __restrict__ in,
                                                   u16* __restrict__ out, int R, int C) {
  __shared__ float tile[64][65];
  const int e = blockIdx.z;
  const float* I = in + (size_t)e * R * C;
  u16* Oo = out + (size_t)e * R * C;
  const int c0 = blockIdx.x * 64, r0 = blockIdx.y * 64;
  const int t = threadIdx.x;
  const int rr = t >> 4;          // 0..15
  const int c4 = (t & 15) << 2;   // 0..60 step 4
#pragma unroll
  for (int j = 0; j < 4; j++) {
    int r = rr + j * 16;
    float4 v = *(const float4*)&I[(size_t)(r0 + r) * C + c0 + c4];
    tile[r][c4] = v.x; tile[r][c4 + 1] = v.y; tile[r][c4 + 2] = v.z; tile[r][c4 + 3] = v.w;
  }
  __syncthreads();
  const int cc = t >> 3;          // 0..31
  const int rb = (t & 7) << 3;    // 0..56 step 8
#pragma unroll
  for (int j = 0; j < 2; j++) {
    int c = cc + j * 32;
    ushort8 o;
#pragma unroll
    for (int k = 0; k < 8; k++) o[k] = f2bf(tile[rb + k][c]);
    *(ushort8*)&Oo[(size_t)(c0 + c) * R + r0 + rb] = o;
  }
}

// ---------------- router: per-token top-2 + gates (deterministic) ----------------
__global__ void router_k(const float* __restrict__ x, const float* __restrict__ Wr,
                         const float* __restrict__ br, int* __restrict__ eidx,
                         float2* __restrict__ gpair) {
  const int t = blockIdx.x;
  const int lane = threadIdx.x;   // 64 threads = 1 wave
  const float* xr = x + (size_t)t * KD;
  double acc[KE];
#pragma unroll
  for (int e = 0; e < KE; e++) acc[e] = 0.0;
  for (int i = lane; i < KD; i += 64) {
    float xv = xr[i];
    const float* wr = Wr + i * KE;
#pragma unroll
    for (int e = 0; e < KE; e++) acc[e] += (double)xv * (double)wr[e];
  }
#pragma unroll
  for (int e = 0; e < KE; e++) {
#pragma unroll
    for (int m = 32; m > 0; m >>= 1) acc[e] += __shfl_xor(acc[e], m, 64);
  }
  if (lane == 0) {
    float l[KE];
#pragma unroll
    for (int e = 0; e < KE; e++) l[e] = (float)acc[e] + br[e];
    int i0 = 0;
#pragma unroll
    for (int e = 1; e < KE; e++) if (l[e] > l[i0]) i0 = e;
    int i1 = -1;
#pragma unroll
    for (int e = 0; e < KE; e++) {
      if (e == i0) continue;
      if (i1 < 0 || l[e] > l[i1]) i1 = e;
    }
    float g0 = 1.0f / (1.0f + expf(l[i1] - l[i0]));
    eidx[t] = i0 | (i1 << 4);
    gpair[t] = make_float2(g0, 1.0f - g0);
  }
}

// ------- bucket: deterministic per-expert compaction; pos[2t+rank] = slot-within-expert -------
__global__ __launch_bounds__(256) void bucket_k(const int* __restrict__ eidx,
                                                int* __restrict__ cnt,
                                                int* __restrict__ tok,
                                                int* __restrict__ pos) {
  const int e = blockIdx.x;
  const int tid = threadIdx.x;       // 256 threads, 16 tokens each
  const int t0 = tid * 16;
  int f[16]; int c = 0;
#pragma unroll
  for (int j = 0; j < 16; j++) {
    int pk = eidx[t0 + j];
    int h0 = ((pk & 15) == e);
    int h1 = (((pk >> 4) & 15) == e);
    f[j] = h0 ? 1 : (h1 ? 2 : 0);    // 0=absent, 1=rank0, 2=rank1
    c += (f[j] != 0);
  }
  __shared__ int sc[256];
  sc[tid] = c;
  __syncthreads();
  for (int d = 1; d < 256; d <<= 1) {
    int add = (tid >= d) ? sc[tid - d] : 0;
    __syncthreads();
    sc[tid] += add;
    __syncthreads();
  }
  int base = sc[tid] - c;            // exclusive prefix
  if (tid == 0) cnt[e] = sc[255];
#pragma unroll
  for (int j = 0; j < 16; j++) {
    if (f[j]) {
      tok[(e << 12) + base] = t0 + j;
      pos[2 * (t0 + j) + (f[j] - 1)] = base;
      base++;
    }
  }
}

__global__ void offsets_k(const int* __restrict__ cnt, int* __restrict__ offs) {
  if (threadIdx.x == 0 && blockIdx.x == 0) {
    int s = 0;
#pragma unroll
    for (int e = 0; e < KE; e++) { offs[e] = s; s += cnt[e]; }
  }
}

// ---------------- GEMM1: h = relu(gather(x) @ W1 + b1) -> hbuf bf16 ----------------
// BM=BN=256, BK=32, 512 threads = 8 waves (2Mx4N), wave tile 128x64 (acc[8][4]).
// 4 LDS buffers (128 KB), stage 3 K-tiles ahead, counted vmcnt(12) (never 0 in loop).
// Linear LDS [256][32] u16: 64B row stride puts a wave's b128 column reads at the
// uniform 8-access/bank BW floor -> no swizzle needed.
__global__ __launch_bounds__(512, 2) void gemm1_k(
    const u16* __restrict__ xbf, const u16* __restrict__ w1t,
    const float* __restrict__ b1, const int* __restrict__ cnt,
    const int* __restrict__ offs, const int* __restrict__ tok,
    u16* __restrict__ hbuf) {
  const int e = blockIdx.z;
  const int me = cnt[e];
  const int m0 = blockIdx.y * 256;
  if (m0 >= me) return;
  const int n0 = blockIdx.x * 256;
  const int oe = offs[e];
  const int* tk = tok + (e << 12);

  __shared__ u16 As[4 * 8192];   // 4 bufs x [256 rows][32 k]
  __shared__ u16 Bs[4 * 8192];

  const int tid = threadIdx.x;
  const int lane = tid & 63;
  const int w = tid >> 6;            // 0..7
  const int wm = w >> 2, wn = w & 3; // 2 x 4 wave grid

  // staging: per tile each thread does 2 A + 2 B glds16.
  // 16B-slot idx = w*128 + j*64 + lane  ->  row = w*32 + j*16 + (lane>>2), slot = lane&3
  const int srow = w * 32 + (lane >> 2);
  const int scol = (lane & 3) << 3;               // k offset (u16) of this lane's 16B slot
  const int gr0 = m0 + srow, gr1 = gr0 + 16;
  const int ta0 = (gr0 < me) ? tk[gr0] : 0;
  const int ta1 = (gr1 < me) ? tk[gr1] : 0;
  const u16* gA0 = xbf + ((size_t)ta0 << 10) + scol;
  const u16* gA1 = xbf + ((size_t)ta1 << 10) + scol;
  const u16* gB0 = w1t + ((size_t)e << 22) + ((size_t)(n0 + srow) << 10) + scol;
  const u16* gB1 = gB0 + (16 << 10);
  u16* lA0 = As + w * 1024 + lane * 8;   // j=0 dest; j=1 = +512
  u16* lB0 = Bs + w * 1024 + lane * 8;

  floatx4 acc[8][4] = {};
  const int fr = lane & 15;
  const int q  = lane >> 4;
  const int aoff = (wm * 128 + fr) * 32 + q * 8;  // A frag base (u16)
  const int boff = (wn * 64  + fr) * 32 + q * 8;  // B frag base

  auto stage = [&](int t) {
    const int buf = (t & 3) * 8192;
    const int k = t * 32;
    glds16(gA0 + k, lA0 + buf);
    glds16(gA1 + k, lA0 + buf + 512);
    glds16(gB0 + k, lB0 + buf);
    glds16(gB1 + k, lB0 + buf + 512);
  };
  auto compute = [&](int t) {
    const int buf = (t & 3) * 8192;
    __builtin_amdgcn_s_setprio(1);
    bf16x8 a[8], b[4];
#pragma unroll
    for (int ni = 0; ni < 4; ni++)
      b[ni] = __builtin_bit_cast(bf16x8, *(const ushort8*)&Bs[buf + boff + ni * 512]);
#pragma unroll
    for (int mi = 0; mi < 8; mi++)
      a[mi] = __builtin_bit_cast(bf16x8, *(const ushort8*)&As[buf + aoff + mi * 512]);
#pragma unroll
    for (int mi = 0; mi < 8; mi++)
#pragma unroll
      for (int ni = 0; ni < 4; ni++)
        acc[mi][ni] = __builtin_amdgcn_mfma_f32_16x16x32_bf16(a[mi], b[ni], acc[mi][ni], 0, 0, 0);
    __builtin_amdgcn_s_setprio(0);
  };

  const int NT = KD / 32;   // 32 K-tiles
  stage(0); stage(1); stage(2);   // 12 vmem ops in flight
  for (int t = 0; t < NT - 3; ++t) {
    stage(t + 3);                                        // 16 in flight
    asm volatile("s_waitcnt vmcnt(12)" ::: "memory");    // tile t landed (mine)
    BAR; SB0;                                            // all waves' tile t landed
    compute(t);
    SB0; BAR;                                            // all reads of buf(t) done
  }
  asm volatile("s_waitcnt vmcnt(8)" ::: "memory");
  BAR; SB0; compute(NT - 3); SB0; BAR;
  asm volatile("s_waitcnt vmcnt(4)" ::: "memory");
  BAR; SB0; compute(NT - 2); SB0; BAR;
  asm volatile("s_waitcnt vmcnt(0)" ::: "memory");
  BAR; SB0; compute(NT - 1);

  // epilogue: C frag (col=lane&15, row=q*4+r)
#pragma unroll
  for (int ni = 0; ni < 4; ni++) {
    const int gcol = n0 + wn * 64 + ni * 16 + fr;
    const float bb = b1[(e << 12) + gcol];
#pragma unroll
    for (int mi = 0; mi < 8; mi++) {
#pragma unroll
      for (int r = 0; r < 4; r++) {
        const int gr = m0 + wm * 128 + mi * 16 + q * 4 + r;
        if (gr < me) {
          float v = fmaxf(acc[mi][ni][r] + bb, 0.0f);
          hbuf[((size_t)(oe + gr) << 12) + gcol] = f2bf(v);
        }
      }
    }
  }
}

// ------- GEMM2: y[ks][slot][:] = hbuf @ W2 (raw, no bias/gate). split-K=2 -------
// same 256x256/BK32/4-buffer counted-vmcnt structure as gemm1.
__global__ __launch_bounds__(512, 2) void gemm2_k(
    const u16* __restrict__ hbuf, const u16* __restrict__ w2t,
    const int* __restrict__ cnt, const int* __restrict__ offs,
    float* __restrict__ y) {
  const int e = blockIdx.z;
  const int me = cnt[e];
  const int m0 = blockIdx.y * 256;
  if (m0 >= me) return;
  const int ks = blockIdx.x & 1;
  const int n0 = (blockIdx.x >> 1) * 256;
  const int k0 = ks * (KH / 2);
  const int oe = offs[e];

  __shared__ u16 As[4 * 8192];
  __shared__ u16 Bs[4 * 8192];

  const int tid = threadIdx.x;
  const int lane = tid & 63;
  const int w = tid >> 6;
  const int wm = w >> 2, wn = w & 3;

  const int srow = w * 32 + (lane >> 2);
  const int scol = (lane & 3) << 3;
  const int ar0 = m0 + srow, ar1 = ar0 + 16;
  const int sl0 = oe + ((ar0 < me) ? ar0 : 0);
  const int sl1 = oe + ((ar1 < me) ? ar1 : 0);
  const u16* gA0 = hbuf + ((size_t)sl0 << 12) + k0 + scol;
  const u16* gA1 = hbuf + ((size_t)sl1 << 12) + k0 + scol;
  const u16* gB0 = w2t + ((size_t)e << 22) + ((size_t)(n0 + srow) << 12) + k0 + scol;
  const u16* gB1 = gB0 + (16 << 12);
  u16* lA0 = As + w * 1024 + lane * 8;
  u16* lB0 = Bs + w * 1024 + lane * 8;

  floatx4 acc[8][4] = {};
  const int fr = lane & 15;
  const int q  = lane >> 4;
  const int aoff = (wm * 128 + fr) * 32 + q * 8;
  const int boff = (wn * 64  + fr) * 32 + q * 8;

  auto stage = [&](int t) {
    const int buf = (t & 3) * 8192;
    const int k = t * 32;
    glds16(gA0 + k, lA0 + buf);
    glds16(gA1 + k, lA0 + buf + 512);
    glds16(gB0 + k, lB0 + buf);
    glds16(gB1 + k, lB0 + buf + 512);
  };
  auto compute = [&](int t) {
    const int buf = (t & 3) * 8192;
    __builtin_amdgcn_s_setprio(1);
    bf16x8 a[8], b[4];
#pragma unroll
    for (int ni = 0; ni < 4; ni++)
      b[ni] = __builtin_bit_cast(bf16x8, *(const ushort8*)&Bs[buf + boff + ni * 512]);
#pragma unroll
    for (int mi = 0; mi < 8; mi++)
      a[mi] = __builtin_bit_cast(bf16x8, *(const ushort8*)&As[buf + aoff + mi * 512]);
#pragma unroll
    for (int mi = 0; mi < 8; mi++)
#pragma unroll
      for (int ni = 0; ni < 4; ni++)
        acc[mi][ni] = __builtin_amdgcn_mfma_f32_16x16x32_bf16(a[mi], b[ni], acc[mi][ni], 0, 0, 0);
    __builtin_amdgcn_s_setprio(0);
  };

  const int NT = (KH / 2) / 32;   // 64 K-tiles
  stage(0); stage(1); stage(2);
  for (int t = 0; t < NT - 3; ++t) {
    stage(t + 3);
    asm volatile("s_waitcnt vmcnt(12)" ::: "memory");
    BAR; SB0;
    compute(t);
    SB0; BAR;
  }
  asm volatile("s_waitcnt vmcnt(8)" ::: "memory");
  BAR; SB0; compute(NT - 3); SB0; BAR;
  asm volatile("s_waitcnt vmcnt(4)" ::: "memory");
  BAR; SB0; compute(NT - 2); SB0; BAR;
  asm volatile("s_waitcnt vmcnt(0)" ::: "memory");
  BAR; SB0; compute(NT - 1);

  float* yk = y + ((size_t)ks << 23);   // 8192*1024 = 1<<23
#pragma unroll
  for (int mi = 0; mi < 8; mi++) {
#pragma unroll
    for (int r = 0; r < 4; r++) {
      const int gr = m0 + wm * 128 + mi * 16 + q * 4 + r;
      if (gr < me) {
        float* yrow = yk + ((size_t)(oe + gr) << 10);
#pragma unroll
        for (int ni = 0; ni < 4; ni++)
          yrow[n0 + wn * 64 + ni * 16 + fr] = acc[mi][ni][r];
      }
    }
  }
}

// ------- combine: out[t] = sum_r g_r * (y0[s_r] + y1[s_r] + b2[e_r]) -------
__global__ __launch_bounds__(256) void combine_k(
    const float* __restrict__ y, const int* __restrict__ eidx,
    const float2* __restrict__ gp, const int* __restrict__ offs,
    const int* __restrict__ pos, const float* __restrict__ b2,
    float* __restrict__ out) {
  const int t = blockIdx.x;
  const int c4 = threadIdx.x << 2;
  const int pk = eidx[t];
  const int e0 = pk & 15, e1 = (pk >> 4) & 15;
  const float2 g = gp[t];
  const int s0 = offs[e0] + pos[2 * t];
  const int s1 = offs[e1] + pos[2 * t + 1];
  float4 a0 = *(const float4*)(y + ((size_t)s0 << 10) + c4);
  float4 a1 = *(const float4*)(y + (1ull << 23) + ((size_t)s0 << 10) + c4);
  float4 c0 = *(const float4*)(y + ((size_t)s1 << 10) + c4);
  float4 c1 = *(const float4*)(y + (1ull << 23) + ((size_t)s1 << 10) + c4);
  float4 ba = *(const float4*)(b2 + (e0 << 10) + c4);
  float4 bc = *(const float4*)(b2 + (e1 << 10) + c4);
  float4 o;
  o.x = g.x * (a0.x + a1.x + ba.x) + g.y * (c0.x + c1.x + bc.x);
  o.y = g.x * (a0.y + a1.y + ba.y) + g.y * (c0.y + c1.y + bc.y);
  o.z = g.x * (a0.z + a1.z + ba.z) + g.y * (c0.z + c1.z + bc.z);
  o.w = g.x * (a0.w + a1.w + ba.w) + g.y * (c0.w + c1.w + bc.w);
  *(float4*)(out + ((size_t)t << 10) + c4) = o;
}

extern "C" void kernel_launch(void* const* d_in, const int* in_sizes, int n_in,
                              void* d_out, int out_size, void* d_ws, size_t ws_size,
                              hipStream_t stream) {
  const float* x  = (const float*)d_in[0];
  const float* Wr = (const float*)d_in[1];
  const float* br = (const float*)d_in[2];
  const float* W1 = (const float*)d_in[3];
  const float* b1 = (const float*)d_in[4];
  const float* W2 = (const float*)d_in[5];
  const float* b2 = (const float*)d_in[6];
  float* out = (float*)d_out;

  char* ws = (char*)d_ws;
  size_t p = 0;
  auto alloc = [&](size_t bytes) {
    void* r = ws + p;
    p = (p + bytes + 255) & ~(size_t)255;
    return r;
  };
  int*    cnt   = (int*)alloc(KE * 4);
  int*    offs  = (int*)alloc(KE * 4);
  int*    eidx  = (int*)alloc((size_t)KT * 4);
  float2* gpair = (float2*)alloc((size_t)KT * 8);
  int*    pos   = (int*)alloc((size_t)2 * KT * 4);
  int*    tok   = (int*)alloc((size_t)KE * KT * 4);
  u16*    xbf   = (u16*)alloc((size_t)KT * KD * 2);
  u16*    w1t   = (u16*)alloc((size_t)KE * KD * KH * 2);   // 64 MB; dead after gemm1
  u16*    w2t   = (u16*)alloc((size_t)KE * KH * KO * 2);
  u16*    hbuf  = (u16*)alloc((size_t)2 * KT * KH * 2);
  float*  y     = (float*)w1t;   // overlay: y[2][8192][1024] fp32 = 64 MB reuses w1t

  cvt_x_k<<<(KT * KD / 4) / 256, 256, 0, stream>>>(x, xbf);
  transpose_k<<<dim3(KH / 64, KD / 64, KE), 256, 0, stream>>>(W1, w1t, KD, KH);
  transpose_k<<<dim3(KO / 64, KH / 64, KE), 256, 0, stream>>>(W2, w2t, KH, KO);
  router_k<<<KT, 64, 0, stream>>>(x, Wr, br, eidx, gpair);
  bucket_k<<<KE, 256, 0, stream>>>(eidx, cnt, tok, pos);
  offsets_k<<<1, 64, 0, stream>>>(cnt, offs);
  gemm1_k<<<dim3(KH / 256, KT / 256, KE), 512, 0, stream>>>(xbf, w1t, b1, cnt, offs, tok, hbuf);
  gemm2_k<<<dim3(2 * KO / 256, KT / 256, KE), 512, 0, stream>>>(hbuf, w2t, cnt, offs, y);
  combine_k<<<KT, 256, 0, stream>>>(y, eidx, gpair, offs, pos, b2, out);
}

// Round 3
// 660.558 us; speedup vs baseline: 1.0195x; 1.0195x over previous
//
#include <hip/hip_runtime.h>
#include <stdint.h>

// ---- problem dims ----
#define KD 1024   // input dim
#define KH 4096   // hidden dim
#define KO 1024   // expert output dim
#define KE 8      // experts
#define KT 4096   // tokens (B*S = 2*2048)

typedef unsigned short u16;
typedef __bf16 bf16x8 __attribute__((ext_vector_type(8)));
typedef unsigned short ushort8 __attribute__((ext_vector_type(8)));
typedef float floatx4 __attribute__((ext_vector_type(4)));

__device__ __forceinline__ u16 f2bf(float f) {
  unsigned u = __float_as_uint(f);
  u += 0x7fffu + ((u >> 16) & 1u);   // round-to-nearest-even
  return (u16)(u >> 16);
}

// direct global->LDS DMA, 16B per lane (HW dest = wave-uniform base + lane*16B)
__device__ __forceinline__ void glds16(const u16* g, u16* l) {
  __builtin_amdgcn_global_load_lds(
      (const __attribute__((address_space(1))) unsigned int*)(g),
      (__attribute__((address_space(3))) unsigned int*)(l), 16, 0, 0);
}

#define BAR __builtin_amdgcn_s_barrier()
#define SB0 __builtin_amdgcn_sched_barrier(0)

// ---------------- x -> bf16 ----------------
__global__ void cvt_x_k(const float* __restrict__ x, u16* __restrict__ xbf) {
  int i = blockIdx.x * blockDim.x + threadIdx.x;   // one float4 per thread
  float4 v = ((const float4*)x)[i];
  union { u16 u[4]; uint2 v2; } o;
  o.u[0] = f2bf(v.x); o.u[1] = f2bf(v.y); o.u[2] = f2bf(v.z); o.u[3] = f2bf(v.w);
  ((uint2*)xbf)[i] = o.v2;
}

// ------- transpose + convert: in[E][R][C] f32 -> out[E][C][R] bf16, 64x64 tiles -------
__global__ __launch_bounds__(256) void transpose_k(const float* __restrict__ in,
                                                   u16* __restrict__ out, int R, int C) {
  __shared__ float tile[64][65];
  const int e = blockIdx.z;
  const float* I = in + (size_t)e * R * C;
  u16* Oo = out + (size_t)e * R * C;
  const int c0 = blockIdx.x * 64, r0 = blockIdx.y * 64;
  const int t = threadIdx.x;
  const int rr = t >> 4;          // 0..15
  const int c4 = (t & 15) << 2;   // 0..60 step 4
#pragma unroll
  for (int j = 0; j < 4; j++) {
    int r = rr + j * 16;
    float4 v = *(const float4*)&I[(size_t)(r0 + r) * C + c0 + c4];
    tile[r][c4] = v.x; tile[r][c4 + 1] = v.y; tile[r][c4 + 2] = v.z; tile[r][c4 + 3] = v.w;
  }
  __syncthreads();
  const int cc = t >> 3;          // 0..31
  const int rb = (t & 7) << 3;    // 0..56 step 8
#pragma unroll
  for (int j = 0; j < 2; j++) {
    int c = cc + j * 32;
    ushort8 o;
#pragma unroll
    for (int k = 0; k < 8; k++) o[k] = f2bf(tile[rb + k][c]);
    *(ushort8*)&Oo[(size_t)(c0 + c) * R + r0 + rb] = o;
  }
}

// ---------------- router: per-token top-2 + gates (deterministic) ----------------
__global__ void router_k(const float* __restrict__ x, const float* __restrict__ Wr,
                         const float* __restrict__ br, int* __restrict__ eidx,
                         float2* __restrict__ gpair) {
  const int t = blockIdx.x;
  const int lane = threadIdx.x;   // 64 threads = 1 wave
  const float* xr = x + (size_t)t * KD;
  double acc[KE];
#pragma unroll
  for (int e = 0; e < KE; e++) acc[e] = 0.0;
  for (int i = lane; i < KD; i += 64) {
    float xv = xr[i];
    const float* wr = Wr + i * KE;
#pragma unroll
    for (int e = 0; e < KE; e++) acc[e] += (double)xv * (double)wr[e];
  }
#pragma unroll
  for (int e = 0; e < KE; e++) {
#pragma unroll
    for (int m = 32; m > 0; m >>= 1) acc[e] += __shfl_xor(acc[e], m, 64);
  }
  if (lane == 0) {
    float l[KE];
#pragma unroll
    for (int e = 0; e < KE; e++) l[e] = (float)acc[e] + br[e];
    int i0 = 0;
#pragma unroll
    for (int e = 1; e < KE; e++) if (l[e] > l[i0]) i0 = e;
    int i1 = -1;
#pragma unroll
    for (int e = 0; e < KE; e++) {
      if (e == i0) continue;
      if (i1 < 0 || l[e] > l[i1]) i1 = e;
    }
    float g0 = 1.0f / (1.0f + expf(l[i1] - l[i0]));
    eidx[t] = i0 | (i1 << 4);
    gpair[t] = make_float2(g0, 1.0f - g0);
  }
}

// ------- bucket: deterministic per-expert compaction; pos[2t+rank] = slot-within-expert -------
__global__ __launch_bounds__(256) void bucket_k(const int* __restrict__ eidx,
                                                int* __restrict__ cnt,
                                                int* __restrict__ tok,
                                                int* __restrict__ pos) {
  const int e = blockIdx.x;
  const int tid = threadIdx.x;       // 256 threads, 16 tokens each
  const int t0 = tid * 16;
  int f[16]; int c = 0;
#pragma unroll
  for (int j = 0; j < 16; j++) {
    int pk = eidx[t0 + j];
    int h0 = ((pk & 15) == e);
    int h1 = (((pk >> 4) & 15) == e);
    f[j] = h0 ? 1 : (h1 ? 2 : 0);    // 0=absent, 1=rank0, 2=rank1
    c += (f[j] != 0);
  }
  __shared__ int sc[256];
  sc[tid] = c;
  __syncthreads();
  for (int d = 1; d < 256; d <<= 1) {
    int add = (tid >= d) ? sc[tid - d] : 0;
    __syncthreads();
    sc[tid] += add;
    __syncthreads();
  }
  int base = sc[tid] - c;            // exclusive prefix
  if (tid == 0) cnt[e] = sc[255];
#pragma unroll
  for (int j = 0; j < 16; j++) {
    if (f[j]) {
      tok[(e << 12) + base] = t0 + j;
      pos[2 * (t0 + j) + (f[j] - 1)] = base;
      base++;
    }
  }
}

__global__ void offsets_k(const int* __restrict__ cnt, int* __restrict__ offs) {
  if (threadIdx.x == 0 && blockIdx.x == 0) {
    int s = 0;
#pragma unroll
    for (int e = 0; e < KE; e++) { offs[e] = s; s += cnt[e]; }
  }
}

// ---------------- GEMM1: h = relu(gather(x) @ W1 + b1) -> hbuf bf16 ----------------
// BM=BN=256, BK=32, 512 threads = 8 waves (2Mx4N), wave tile 128x64 (acc[8][4]).
// 4 LDS buffers (128 KB), stage 3 K-tiles ahead, counted vmcnt(12) (never 0 in loop).
// k-slot XOR swizzle: LDS[row][c] = G[row][c ^ ((row>>1)&3)] (16B slots), applied on
// the glds SOURCE address (dest must stay linear) and on the ds_read slot. This turns
// the 8-way bank conflict of the 64B-row-stride layout into the free 2-way floor.
__global__ __launch_bounds__(512, 2) void gemm1_k(
    const u16* __restrict__ xbf, const u16* __restrict__ w1t,
    const float* __restrict__ b1, const int* __restrict__ cnt,
    const int* __restrict__ offs, const int* __restrict__ tok,
    u16* __restrict__ hbuf) {
  const int e = blockIdx.z;
  const int me = cnt[e];
  const int m0 = blockIdx.y * 256;
  if (m0 >= me) return;
  const int n0 = blockIdx.x * 256;
  const int oe = offs[e];
  const int* tk = tok + (e << 12);

  __shared__ u16 As[4 * 8192];   // 4 bufs x [256 rows][32 k]
  __shared__ u16 Bs[4 * 8192];

  const int tid = threadIdx.x;
  const int lane = tid & 63;
  const int w = tid >> 6;            // 0..7
  const int wm = w >> 2, wn = w & 3; // 2 x 4 wave grid

  // staging: per tile each thread does 2 A + 2 B glds16.
  // lane -> row = w*32 + (lane>>2) (+16 for j=1), 16B slot = lane&3.
  // swizzle s(row) = (row>>1)&3 is identical for row and row+16.
  const int srow = w * 32 + (lane >> 2);
  const int ssw  = (srow >> 1) & 3;
  const int scol = (((lane & 3) ^ ssw) << 3);     // pre-swizzled source k offset (u16)
  const int gr0 = m0 + srow, gr1 = gr0 + 16;
  const int ta0 = (gr0 < me) ? tk[gr0] : 0;
  const int ta1 = (gr1 < me) ? tk[gr1] : 0;
  const u16* gA0 = xbf + ((size_t)ta0 << 10) + scol;
  const u16* gA1 = xbf + ((size_t)ta1 << 10) + scol;
  const u16* gB0 = w1t + ((size_t)e << 22) + ((size_t)(n0 + srow) << 10) + scol;
  const u16* gB1 = gB0 + (16 << 10);
  u16* lA0 = As + w * 1024 + lane * 8;   // linear dest; j=1 = +512
  u16* lB0 = Bs + w * 1024 + lane * 8;

  floatx4 acc[8][4] = {};
  const int fr = lane & 15;
  const int q  = lane >> 4;
  const int ksw = (q ^ ((fr >> 1) & 3)) << 3;     // swizzled read slot (u16 offset)
  const int aoff = (wm * 128 + fr) * 32 + ksw;    // A frag base; +512 per mi
  const int boff = (wn * 64  + fr) * 32 + ksw;    // B frag base; +512 per ni

  auto stage = [&](int t) {
    const int buf = (t & 3) * 8192;
    const int k = t * 32;
    glds16(gA0 + k, lA0 + buf);
    glds16(gA1 + k, lA0 + buf + 512);
    glds16(gB0 + k, lB0 + buf);
    glds16(gB1 + k, lB0 + buf + 512);
  };
  auto compute = [&](int t) {
    const int buf = (t & 3) * 8192;
    __builtin_amdgcn_s_setprio(1);
    bf16x8 a[8], b[4];
#pragma unroll
    for (int ni = 0; ni < 4; ni++)
      b[ni] = __builtin_bit_cast(bf16x8, *(const ushort8*)&Bs[buf + boff + ni * 512]);
#pragma unroll
    for (int mi = 0; mi < 8; mi++)
      a[mi] = __builtin_bit_cast(bf16x8, *(const ushort8*)&As[buf + aoff + mi * 512]);
#pragma unroll
    for (int mi = 0; mi < 8; mi++)
#pragma unroll
      for (int ni = 0; ni < 4; ni++)
        acc[mi][ni] = __builtin_amdgcn_mfma_f32_16x16x32_bf16(a[mi], b[ni], acc[mi][ni], 0, 0, 0);
    __builtin_amdgcn_s_setprio(0);
  };

  const int NT = KD / 32;   // 32 K-tiles
  stage(0); stage(1); stage(2);   // 12 vmem ops in flight
  for (int t = 0; t < NT - 3; ++t) {
    stage(t + 3);                                        // 16 in flight
    asm volatile("s_waitcnt vmcnt(12)" ::: "memory");    // tile t landed (mine)
    BAR; SB0;                                            // all waves' tile t landed
    compute(t);
    SB0; BAR;                                            // all reads of buf(t) done
  }
  asm volatile("s_waitcnt vmcnt(8)" ::: "memory");
  BAR; SB0; compute(NT - 3); SB0; BAR;
  asm volatile("s_waitcnt vmcnt(4)" ::: "memory");
  BAR; SB0; compute(NT - 2); SB0; BAR;
  asm volatile("s_waitcnt vmcnt(0)" ::: "memory");
  BAR; SB0; compute(NT - 1);

  // epilogue: C frag (col=lane&15, row=q*4+r)
#pragma unroll
  for (int ni = 0; ni < 4; ni++) {
    const int gcol = n0 + wn * 64 + ni * 16 + fr;
    const float bb = b1[(e << 12) + gcol];
#pragma unroll
    for (int mi = 0; mi < 8; mi++) {
#pragma unroll
      for (int r = 0; r < 4; r++) {
        const int gr = m0 + wm * 128 + mi * 16 + q * 4 + r;
        if (gr < me) {
          float v = fmaxf(acc[mi][ni][r] + bb, 0.0f);
          hbuf[((size_t)(oe + gr) << 12) + gcol] = f2bf(v);
        }
      }
    }
  }
}

// ------- GEMM2: y[ks][slot][:] = hbuf @ W2 (raw, no bias/gate). split-K=2 -------
// same 256x256/BK32/4-buffer counted-vmcnt + k-slot swizzle structure as gemm1.
__global__ __launch_bounds__(512, 2) void gemm2_k(
    const u16* __restrict__ hbuf, const u16* __restrict__ w2t,
    const int* __restrict__ cnt, const int* __restrict__ offs,
    float* __restrict__ y) {
  const int e = blockIdx.z;
  const int me = cnt[e];
  const int m0 = blockIdx.y * 256;
  if (m0 >= me) return;
  const int ks = blockIdx.x & 1;
  const int n0 = (blockIdx.x >> 1) * 256;
  const int k0 = ks * (KH / 2);
  const int oe = offs[e];

  __shared__ u16 As[4 * 8192];
  __shared__ u16 Bs[4 * 8192];

  const int tid = threadIdx.x;
  const int lane = tid & 63;
  const int w = tid >> 6;
  const int wm = w >> 2, wn = w & 3;

  const int srow = w * 32 + (lane >> 2);
  const int ssw  = (srow >> 1) & 3;
  const int scol = (((lane & 3) ^ ssw) << 3);
  const int ar0 = m0 + srow, ar1 = ar0 + 16;
  const int sl0 = oe + ((ar0 < me) ? ar0 : 0);
  const int sl1 = oe + ((ar1 < me) ? ar1 : 0);
  const u16* gA0 = hbuf + ((size_t)sl0 << 12) + k0 + scol;
  const u16* gA1 = hbuf + ((size_t)sl1 << 12) + k0 + scol;
  const u16* gB0 = w2t + ((size_t)e << 22) + ((size_t)(n0 + srow) << 12) + k0 + scol;
  const u16* gB1 = gB0 + (16 << 12);
  u16* lA0 = As + w * 1024 + lane * 8;
  u16* lB0 = Bs + w * 1024 + lane * 8;

  floatx4 acc[8][4] = {};
  const int fr = lane & 15;
  const int q  = lane >> 4;
  const int ksw = (q ^ ((fr >> 1) & 3)) << 3;
  const int aoff = (wm * 128 + fr) * 32 + ksw;
  const int boff = (wn * 64  + fr) * 32 + ksw;

  auto stage = [&](int t) {
    const int buf = (t & 3) * 8192;
    const int k = t * 32;
    glds16(gA0 + k, lA0 + buf);
    glds16(gA1 + k, lA0 + buf + 512);
    glds16(gB0 + k, lB0 + buf);
    glds16(gB1 + k, lB0 + buf + 512);
  };
  auto compute = [&](int t) {
    const int buf = (t & 3) * 8192;
    __builtin_amdgcn_s_setprio(1);
    bf16x8 a[8], b[4];
#pragma unroll
    for (int ni = 0; ni < 4; ni++)
      b[ni] = __builtin_bit_cast(bf16x8, *(const ushort8*)&Bs[buf + boff + ni * 512]);
#pragma unroll
    for (int mi = 0; mi < 8; mi++)
      a[mi] = __builtin_bit_cast(bf16x8, *(const ushort8*)&As[buf + aoff + mi * 512]);
#pragma unroll
    for (int mi = 0; mi < 8; mi++)
#pragma unroll
      for (int ni = 0; ni < 4; ni++)
        acc[mi][ni] = __builtin_amdgcn_mfma_f32_16x16x32_bf16(a[mi], b[ni], acc[mi][ni], 0, 0, 0);
    __builtin_amdgcn_s_setprio(0);
  };

  const int NT = (KH / 2) / 32;   // 64 K-tiles
  stage(0); stage(1); stage(2);
  for (int t = 0; t < NT - 3; ++t) {
    stage(t + 3);
    asm volatile("s_waitcnt vmcnt(12)" ::: "memory");
    BAR; SB0;
    compute(t);
    SB0; BAR;
  }
  asm volatile("s_waitcnt vmcnt(8)" ::: "memory");
  BAR; SB0; compute(NT - 3); SB0; BAR;
  asm volatile("s_waitcnt vmcnt(4)" ::: "memory");
  BAR; SB0; compute(NT - 2); SB0; BAR;
  asm volatile("s_waitcnt vmcnt(0)" ::: "memory");
  BAR; SB0; compute(NT - 1);

  float* yk = y + ((size_t)ks << 23);   // 8192*1024 = 1<<23
#pragma unroll
  for (int mi = 0; mi < 8; mi++) {
#pragma unroll
    for (int r = 0; r < 4; r++) {
      const int gr = m0 + wm * 128 + mi * 16 + q * 4 + r;
      if (gr < me) {
        float* yrow = yk + ((size_t)(oe + gr) << 10);
#pragma unroll
        for (int ni = 0; ni < 4; ni++)
          yrow[n0 + wn * 64 + ni * 16 + fr] = acc[mi][ni][r];
      }
    }
  }
}

// ------- combine: out[t] = sum_r g_r * (y0[s_r] + y1[s_r] + b2[e_r]) -------
__global__ __launch_bounds__(256) void combine_k(
    const float* __restrict__ y, const int* __restrict__ eidx,
    const float2* __restrict__ gp, const int* __restrict__ offs,
    const int* __restrict__ pos, const float* __restrict__ b2,
    float* __restrict__ out) {
  const int t = blockIdx.x;
  const int c4 = threadIdx.x << 2;
  const int pk = eidx[t];
  const int e0 = pk & 15, e1 = (pk >> 4) & 15;
  const float2 g = gp[t];
  const int s0 = offs[e0] + pos[2 * t];
  const int s1 = offs[e1] + pos[2 * t + 1];
  float4 a0 = *(const float4*)(y + ((size_t)s0 << 10) + c4);
  float4 a1 = *(const float4*)(y + (1ull << 23) + ((size_t)s0 << 10) + c4);
  float4 c0 = *(const float4*)(y + ((size_t)s1 << 10) + c4);
  float4 c1 = *(const float4*)(y + (1ull << 23) + ((size_t)s1 << 10) + c4);
  float4 ba = *(const float4*)(b2 + (e0 << 10) + c4);
  float4 bc = *(const float4*)(b2 + (e1 << 10) + c4);
  float4 o;
  o.x = g.x * (a0.x + a1.x + ba.x) + g.y * (c0.x + c1.x + bc.x);
  o.y = g.x * (a0.y + a1.y + ba.y) + g.y * (c0.y + c1.y + bc.y);
  o.z = g.x * (a0.z + a1.z + ba.z) + g.y * (c0.z + c1.z + bc.z);
  o.w = g.x * (a0.w + a1.w + ba.w) + g.y * (c0.w + c1.w + bc.w);
  *(float4*)(out + ((size_t)t << 10) + c4) = o;
}

extern "C" void kernel_launch(void* const* d_in, const int* in_sizes, int n_in,
                              void* d_out, int out_size, void* d_ws, size_t ws_size,
                              hipStream_t stream) {
  const float* x  = (const float*)d_in[0];
  const float* Wr = (const float*)d_in[1];
  const float* br = (const float*)d_in[2];
  const float* W1 = (const float*)d_in[3];
  const float* b1 = (const float*)d_in[4];
  const float* W2 = (const float*)d_in[5];
  const float* b2 = (const float*)d_in[6];
  float* out = (float*)d_out;

  char* ws = (char*)d_ws;
  size_t p = 0;
  auto alloc = [&](size_t bytes) {
    void* r = ws + p;
    p = (p + bytes + 255) & ~(size_t)255;
    return r;
  };
  int*    cnt   = (int*)alloc(KE * 4);
  int*    offs  = (int*)alloc(KE * 4);
  int*    eidx  = (int*)alloc((size_t)KT * 4);
  float2* gpair = (float2*)alloc((size_t)KT * 8);
  int*    pos   = (int*)alloc((size_t)2 * KT * 4);
  int*    tok   = (int*)alloc((size_t)KE * KT * 4);
  u16*    xbf   = (u16*)alloc((size_t)KT * KD * 2);
  u16*    w1t   = (u16*)alloc((size_t)KE * KD * KH * 2);   // 64 MB; dead after gemm1
  u16*    w2t   = (u16*)alloc((size_t)KE * KH * KO * 2);
  u16*    hbuf  = (u16*)alloc((size_t)2 * KT * KH * 2);
  float*  y     = (float*)w1t;   // overlay: y[2][8192][1024] fp32 = 64 MB reuses w1t

  cvt_x_k<<<(KT * KD / 4) / 256, 256, 0, stream>>>(x, xbf);
  transpose_k<<<dim3(KH / 64, KD / 64, KE), 256, 0, stream>>>(W1, w1t, KD, KH);
  transpose_k<<<dim3(KO / 64, KH / 64, KE), 256, 0, stream>>>(W2, w2t, KH, KO);
  router_k<<<KT, 64, 0, stream>>>(x, Wr, br, eidx, gpair);
  bucket_k<<<KE, 256, 0, stream>>>(eidx, cnt, tok, pos);
  offsets_k<<<1, 64, 0, stream>>>(cnt, offs);
  gemm1_k<<<dim3(KH / 256, KT / 256, KE), 512, 0, stream>>>(xbf, w1t, b1, cnt, offs, tok, hbuf);
  gemm2_k<<<dim3(2 * KO / 256, KT / 256, KE), 512, 0, stream>>>(hbuf, w2t, cnt, offs, y);
  combine_k<<<KT, 256, 0, stream>>>(y, eidx, gpair, offs, pos, b2, out);
}